// Round 9
// baseline (365.761 us; speedup 1.0000x reference)
//
#include <hip/hip_runtime.h>

#define RELS 4
#define NGRAPH 256
#define SCAN_BLK 2048   // elements per scan1 block (256 thr x 8)

static inline size_t alignup(size_t x) { return (x + 255) & ~(size_t)255; }

// ---------------------------------------------------------------------------
// CSR build step 1: histogram of segments seg = dst*R + et
// ---------------------------------------------------------------------------
__global__ void hist_kernel(const int* __restrict__ dst, const int* __restrict__ et,
                            int* __restrict__ hcnt, int E)
{
    int e = blockIdx.x * blockDim.x + threadIdx.x;
    if (e < E) atomicAdd(&hcnt[dst[e] * RELS + et[e]], 1);
}

// ---------------------------------------------------------------------------
// CSR build step 2: exclusive scan over NSEG bins (3 kernels)
// ---------------------------------------------------------------------------
__global__ __launch_bounds__(256)
void scan1_kernel(const int* __restrict__ in, int* __restrict__ excl,
                  int* __restrict__ bsum, int n)
{
    __shared__ int lds[256];
    int tid = threadIdx.x;
    int base = blockIdx.x * SCAN_BLK + tid * 8;
    int v[8];
    #pragma unroll
    for (int i = 0; i < 8; ++i) v[i] = (base + i < n) ? in[base + i] : 0;
    int run = 0;
    #pragma unroll
    for (int i = 0; i < 8; ++i) { int t = v[i]; v[i] = run; run += t; }
    lds[tid] = run;
    __syncthreads();
    for (int off = 1; off < 256; off <<= 1) {
        int t = (tid >= off) ? lds[tid - off] : 0;
        __syncthreads();
        lds[tid] += t;
        __syncthreads();
    }
    int ex = (tid > 0) ? lds[tid - 1] : 0;
    if (tid == 255) bsum[blockIdx.x] = lds[255];
    #pragma unroll
    for (int i = 0; i < 8; ++i) if (base + i < n) excl[base + i] = v[i] + ex;
}

__global__ __launch_bounds__(256)
void scan2_kernel(const int* __restrict__ bsum, int* __restrict__ boff, int nb)
{
    __shared__ int lds[256];
    int tid = threadIdx.x;
    lds[tid] = (tid < nb) ? bsum[tid] : 0;
    __syncthreads();
    for (int off = 1; off < 256; off <<= 1) {
        int t = (tid >= off) ? lds[tid - off] : 0;
        __syncthreads();
        lds[tid] += t;
        __syncthreads();
    }
    if (tid < nb) boff[tid] = (tid > 0) ? lds[tid - 1] : 0;
}

// writes BOTH ptr and cursor (cursor starts at segment base -> fill needs no ptr read)
__global__ void scan3_kernel(const int* __restrict__ excl, const int* __restrict__ boff,
                             int* __restrict__ ptr, int* __restrict__ cursor,
                             int n, int total)
{
    int i = blockIdx.x * blockDim.x + threadIdx.x;
    if (i < n) {
        int v = excl[i] + boff[i / SCAN_BLK];
        ptr[i] = v;
        cursor[i] = v;
    }
    if (i == 0) ptr[n] = total;
}

// ---------------------------------------------------------------------------
// CSR build step 3: fill sorted src-node list.
// cursor pre-initialized to segment bases; non-temporal store (ssrc is only
// re-read later, streaming, by the layers — don't pollute/allocate L2).
// ---------------------------------------------------------------------------
__global__ void fill_kernel(const int* __restrict__ src, const int* __restrict__ dst,
                            const int* __restrict__ et,
                            int* __restrict__ cursor, int* __restrict__ ssrc, int E)
{
    int e = blockIdx.x * blockDim.x + threadIdx.x;
    if (e < E) {
        int seg = dst[e] * RELS + et[e];
        int pos = atomicAdd(&cursor[seg], 1);
        __builtin_nontemporal_store(src[e], &ssrc[pos]);
    }
}

// ---------------------------------------------------------------------------
// Fused RGCN layer, wave-specialized compute, 512-thread blocks.
//  Phase 1 (gather): LPN lanes/node (LPN == IN/4: one float4 slice per lane),
//  NPB = 512/LPN nodes/block, 4x-unrolled CSR walk; the 4 relation means go
//  to LDS (row stride 4*IN+1, odd -> conflict-free column reads).
//  Phase 2 (compute): 8 waves; wave w -> node-block (w % NB) and channel
//  group (w / NB), lane = node. Weight rows are wave-uniform -> s_load (SMEM
//  pipe). Root term loads the lane's own feature row from global (L1-hot).
//  All instantiations: ~33 KB LDS -> 4 blocks/CU; __launch_bounds__(512,8)
//  caps VGPR at 64 -> 32 waves/CU (100%) ceiling.
// ---------------------------------------------------------------------------
template<int IN, int OUT, bool RELU, int LPN, int MINW>
__global__ __launch_bounds__(512, MINW)
void rgcn_layer_kernel(const float* __restrict__ feat,
                       const int* __restrict__ ptr, const int* __restrict__ ssrc,
                       const float* __restrict__ W, const float* __restrict__ root,
                       const float* __restrict__ bias,
                       float* __restrict__ hout, int n)
{
    constexpr int TPB = 512;
    constexpr int NPB = TPB / LPN;        // nodes per block (128 or 64)
    constexpr int K   = 4 * IN;           // staged: 4 relation means
    constexpr int AGS = K + 1;            // odd LDS row stride
    constexpr int F4  = IN / 4;           // float4 per feature row (== LPN)
    constexpr int Q   = OUT / LPN;        // channels per thread in phase 2
    constexpr int NB  = NPB / 64;         // node-blocks of 64 (1 or 2)

    static_assert(F4 == LPN, "one float4 slice per lane");

    __shared__ float agg[NPB * AGS];

    const int tid  = (int)threadIdx.x;
    const int nl   = tid / LPN;
    const int c4   = tid % LPN;
    const int node = (int)blockIdx.x * NPB + nl;

    const float4* fv = (const float4*)feat;

    // ---- phase 1: gather ----
    if (node < n) {
        int4 p4  = *(const int4*)(ptr + (size_t)node * RELS);
        int pend = ptr[(size_t)node * RELS + RELS];
        int pb[RELS + 1] = {p4.x, p4.y, p4.z, p4.w, pend};
        float* arow = &agg[nl * AGS];

        #pragma unroll
        for (int r = 0; r < RELS; ++r) {
            float4 ac = {0.f, 0.f, 0.f, 0.f};
            int p0 = pb[r], p1 = pb[r + 1];
            int e = p0;
            for (; e + 4 <= p1; e += 4) {
                int s0 = ssrc[e], s1 = ssrc[e + 1], s2 = ssrc[e + 2], s3 = ssrc[e + 3];
                float4 v0 = fv[(size_t)s0 * F4 + c4];
                float4 v1 = fv[(size_t)s1 * F4 + c4];
                float4 v2 = fv[(size_t)s2 * F4 + c4];
                float4 v3 = fv[(size_t)s3 * F4 + c4];
                ac.x += (v0.x + v1.x) + (v2.x + v3.x);
                ac.y += (v0.y + v1.y) + (v2.y + v3.y);
                ac.z += (v0.z + v1.z) + (v2.z + v3.z);
                ac.w += (v0.w + v1.w) + (v2.w + v3.w);
            }
            for (; e < p1; ++e) {
                int sn = ssrc[e];
                float4 v = fv[(size_t)sn * F4 + c4];
                ac.x += v.x; ac.y += v.y; ac.z += v.z; ac.w += v.w;
            }
            float nm = 1.0f / fmaxf((float)(p1 - p0), 1.0f);
            int kb = r * IN + c4 * 4;
            arow[kb + 0] = ac.x * nm;
            arow[kb + 1] = ac.y * nm;
            arow[kb + 2] = ac.z * nm;
            arow[kb + 3] = ac.w * nm;
        }
    }
    __syncthreads();

    // ---- phase 2: compute (wave -> (node-block, channel-group), lane -> node)
    const int wv   = __builtin_amdgcn_readfirstlane(tid >> 6);
    const int lane = tid & 63;
    const int nb   = wv % NB;             // node block within this workgroup
    const int cg   = wv / NB;             // channel group (wave-uniform)
    const int ln   = nb * 64 + lane;      // local node index
    const int cn   = (int)blockIdx.x * NPB + ln;
    const int cnc  = (cn < n) ? cn : (n - 1);

    const float* __restrict__ wq = W    + cg * Q;   // row stride OUT
    const float* __restrict__ rq = root + cg * Q;
    const float* __restrict__ bq = bias + cg * Q;
    const float* arow = &agg[ln * AGS];

    float acc[Q];
    #pragma unroll
    for (int o = 0; o < Q; ++o) acc[o] = bq[o];

    #pragma unroll 4
    for (int k = 0; k < K; ++k) {
        float m = arow[k];
        const float* wr = wq + (size_t)k * OUT;     // wave-uniform -> s_load
        #pragma unroll
        for (int o = 0; o < Q; ++o) acc[o] += m * wr[o];
    }
    // root term: own feature row, loaded float4-at-a-time (short live range)
    #pragma unroll
    for (int j = 0; j < F4; ++j) {
        float4 v = fv[(size_t)cnc * F4 + j];
        #pragma unroll
        for (int c = 0; c < 4; ++c) {
            float m = (&v.x)[c];
            const float* wr = rq + (size_t)(j * 4 + c) * OUT;   // wave-uniform
            #pragma unroll
            for (int o = 0; o < Q; ++o) acc[o] += m * wr[o];
        }
    }

    if (cn < n) {
        float* ho = hout + (size_t)cn * OUT + cg * Q;
        #pragma unroll
        for (int o = 0; o < Q; o += 4) {
            float4 v;
            v.x = RELU ? fmaxf(acc[o + 0], 0.f) : acc[o + 0];
            v.y = RELU ? fmaxf(acc[o + 1], 0.f) : acc[o + 1];
            v.z = RELU ? fmaxf(acc[o + 2], 0.f) : acc[o + 2];
            v.w = RELU ? fmaxf(acc[o + 3], 0.f) : acc[o + 3];
            *(float4*)(ho + o) = v;
        }
    }
}

// ---------------------------------------------------------------------------
// Segment-max pool: one block per graph, contiguous node range via binary
// search on sorted batch. Register max -> LDS reduce -> plain store.
// ---------------------------------------------------------------------------
__device__ inline int lower_bound_i(const int* a, int n, int key)
{
    int lo = 0, hi = n;
    while (lo < hi) { int mid = (lo + hi) >> 1; if (a[mid] < key) lo = mid + 1; else hi = mid; }
    return lo;
}

__global__ __launch_bounds__(256)
void pool_kernel(const float* __restrict__ h3, const int* __restrict__ batch,
                 float* __restrict__ gpool, int n)
{
    int g = blockIdx.x;
    int t = threadIdx.x;
    int ch = t & 63, q = t >> 6;

    int start = lower_bound_i(batch, n, g);
    int end   = lower_bound_i(batch, n, g + 1);

    float m = -INFINITY;
    for (int r = start + q; r < end; r += 4)
        m = fmaxf(m, h3[(size_t)r * 64 + ch]);

    __shared__ float red[4][64];
    red[q][ch] = m;
    __syncthreads();
    if (q == 0) {
        m = fmaxf(fmaxf(red[0][ch], red[1][ch]), fmaxf(red[2][ch], red[3][ch]));
        gpool[g * 64 + ch] = m;
    }
}

// ---------------------------------------------------------------------------
// MLP head: [G,64] -> 128 (relu) -> 256 (relu) -> 51 -> softmax. 1 block/graph.
// ---------------------------------------------------------------------------
__global__ __launch_bounds__(256)
void mlp_kernel(const float* __restrict__ gpool,
                const float* __restrict__ Wf1, const float* __restrict__ bf1,
                const float* __restrict__ Wh,  const float* __restrict__ bh,
                const float* __restrict__ Wl,  const float* __restrict__ bl,
                float* __restrict__ out)
{
    __shared__ float gin[64];
    __shared__ float f1[128];
    __shared__ float f2[256];
    __shared__ float lg[51];
    int g = blockIdx.x, t = threadIdx.x;

    if (t < 64) gin[t] = gpool[g * 64 + t];
    __syncthreads();

    if (t < 128) {
        float a = bf1[t];
        #pragma unroll 8
        for (int k = 0; k < 64; ++k) a += gin[k] * Wf1[k * 128 + t];
        f1[t] = fmaxf(a, 0.f);
    }
    __syncthreads();

    {
        float a = bh[t];
        #pragma unroll 8
        for (int k = 0; k < 128; ++k) a += f1[k] * Wh[k * 256 + t];
        f2[t] = fmaxf(a, 0.f);
    }
    __syncthreads();

    if (t < 51) {
        float a = bl[t];
        #pragma unroll 8
        for (int k = 0; k < 256; ++k) a += f2[k] * Wl[k * 51 + t];
        lg[t] = a;
    }
    __syncthreads();

    if (t == 0) {
        float m = lg[0];
        for (int i = 1; i < 51; ++i) m = fmaxf(m, lg[i]);
        float ssum = 0.f;
        for (int i = 0; i < 51; ++i) { float e = __expf(lg[i] - m); lg[i] = e; ssum += e; }
        float inv = 1.0f / ssum;
        for (int i = 0; i < 51; ++i) out[g * 51 + i] = lg[i] * inv;
    }
}

// ---------------------------------------------------------------------------
extern "C" void kernel_launch(void* const* d_in, const int* in_sizes, int n_in,
                              void* d_out, int out_size, void* d_ws, size_t ws_size,
                              hipStream_t stream)
{
    const float* x    = (const float*)d_in[0];
    const int*   ei   = (const int*)d_in[1];
    const int*   et   = (const int*)d_in[2];
    const int*   batch= (const int*)d_in[3];
    const float* W1   = (const float*)d_in[4];
    const float* r1   = (const float*)d_in[5];
    const float* b1   = (const float*)d_in[6];
    const float* W2   = (const float*)d_in[7];
    const float* r2   = (const float*)d_in[8];
    const float* b2   = (const float*)d_in[9];
    const float* W3   = (const float*)d_in[10];
    const float* r3   = (const float*)d_in[11];
    const float* b3   = (const float*)d_in[12];
    const float* Wf1  = (const float*)d_in[13];
    const float* bf1  = (const float*)d_in[14];
    const float* Wh   = (const float*)d_in[15];
    const float* bh   = (const float*)d_in[16];
    const float* Wl   = (const float*)d_in[17];
    const float* bl   = (const float*)d_in[18];

    const int N = in_sizes[0] / 16;
    const int E = in_sizes[2];
    const int NSEG = N * RELS;
    const int NBLK = (NSEG + SCAN_BLK - 1) / SCAN_BLK;
    const int* srcp = ei;
    const int* dstp = ei + E;

    char* ws = (char*)d_ws;
    size_t off = 0;
    int*   hcnt   = (int*)(ws + off);   off += alignup((size_t)NSEG * 4);
    int*   ptr    = (int*)(ws + off);   off += alignup((size_t)(NSEG + 1) * 4);
    int*   excl   = (int*)(ws + off);   off += alignup((size_t)NSEG * 4);
    int*   bsum   = (int*)(ws + off);   off += alignup(256 * 4);
    int*   boff   = (int*)(ws + off);   off += alignup(256 * 4);
    int*   cursor = (int*)(ws + off);   off += alignup((size_t)NSEG * 4);
    int*   ssrc   = (int*)(ws + off);   off += alignup((size_t)E * 4);
    float* h1     = (float*)(ws + off); off += alignup((size_t)N * 16 * 4);
    float* h2     = (float*)(ws + off); off += alignup((size_t)N * 32 * 4);
    float* h3     = (float*)(ws + off); off += alignup((size_t)N * 64 * 4);
    float* gpool  = (float*)(ws + off); off += alignup((size_t)NGRAPH * 64 * 4);
    (void)ws_size; (void)n_in; (void)out_size;

    // ---- build CSR (once per call; reused by all 3 layers)
    (void)hipMemsetAsync(hcnt, 0, (size_t)NSEG * 4, stream);
    hist_kernel<<<(E + 255) / 256, 256, 0, stream>>>(dstp, et, hcnt, E);
    scan1_kernel<<<NBLK, 256, 0, stream>>>(hcnt, excl, bsum, NSEG);
    scan2_kernel<<<1, 256, 0, stream>>>(bsum, boff, NBLK);
    scan3_kernel<<<(NSEG + 255) / 256, 256, 0, stream>>>(excl, boff, ptr, cursor, NSEG, E);
    fill_kernel<<<(E + 255) / 256, 256, 0, stream>>>(srcp, dstp, et, cursor, ssrc, E);

    // ---- three fused gather+transform layers (512-thread blocks)
    rgcn_layer_kernel<16, 16, true, 4, 8><<<(N + 127) / 128, 512, 0, stream>>>(
        x, ptr, ssrc, W1, r1, b1, h1, N);
    rgcn_layer_kernel<16, 32, true, 4, 8><<<(N + 127) / 128, 512, 0, stream>>>(
        h1, ptr, ssrc, W2, r2, b2, h2, N);
    rgcn_layer_kernel<32, 64, false, 8, 8><<<(N + 63) / 64, 512, 0, stream>>>(
        h2, ptr, ssrc, W3, r3, b3, h3, N);

    // ---- segment-max pool (no atomics)
    pool_kernel<<<NGRAPH, 256, 0, stream>>>(h3, batch, gpool, N);

    // ---- MLP head + softmax
    mlp_kernel<<<NGRAPH, 256, 0, stream>>>(gpool, Wf1, bf1, Wh, bh, Wl, bl, (float*)d_out);
}

// Round 10
// 357.087 us; speedup vs baseline: 1.0243x; 1.0243x over previous
//
#include <hip/hip_runtime.h>

#define RELS 4
#define NGRAPH 256
#define SCAN_BLK 2048   // elements per scan1 block (256 thr x 8)

static inline size_t alignup(size_t x) { return (x + 255) & ~(size_t)255; }

// ---------------------------------------------------------------------------
// CSR build step 1: histogram of segments seg = dst*R + et
// ---------------------------------------------------------------------------
__global__ void hist_kernel(const int* __restrict__ dst, const int* __restrict__ et,
                            int* __restrict__ hcnt, int E)
{
    int e = blockIdx.x * blockDim.x + threadIdx.x;
    if (e < E) atomicAdd(&hcnt[dst[e] * RELS + et[e]], 1);
}

// ---------------------------------------------------------------------------
// CSR build step 2: exclusive scan over NSEG bins (3 kernels)
// ---------------------------------------------------------------------------
__global__ __launch_bounds__(256)
void scan1_kernel(const int* __restrict__ in, int* __restrict__ excl,
                  int* __restrict__ bsum, int n)
{
    __shared__ int lds[256];
    int tid = threadIdx.x;
    int base = blockIdx.x * SCAN_BLK + tid * 8;
    int v[8];
    #pragma unroll
    for (int i = 0; i < 8; ++i) v[i] = (base + i < n) ? in[base + i] : 0;
    int run = 0;
    #pragma unroll
    for (int i = 0; i < 8; ++i) { int t = v[i]; v[i] = run; run += t; }
    lds[tid] = run;
    __syncthreads();
    for (int off = 1; off < 256; off <<= 1) {
        int t = (tid >= off) ? lds[tid - off] : 0;
        __syncthreads();
        lds[tid] += t;
        __syncthreads();
    }
    int ex = (tid > 0) ? lds[tid - 1] : 0;
    if (tid == 255) bsum[blockIdx.x] = lds[255];
    #pragma unroll
    for (int i = 0; i < 8; ++i) if (base + i < n) excl[base + i] = v[i] + ex;
}

__global__ __launch_bounds__(256)
void scan2_kernel(const int* __restrict__ bsum, int* __restrict__ boff, int nb)
{
    __shared__ int lds[256];
    int tid = threadIdx.x;
    lds[tid] = (tid < nb) ? bsum[tid] : 0;
    __syncthreads();
    for (int off = 1; off < 256; off <<= 1) {
        int t = (tid >= off) ? lds[tid - off] : 0;
        __syncthreads();
        lds[tid] += t;
        __syncthreads();
    }
    if (tid < nb) boff[tid] = (tid > 0) ? lds[tid - 1] : 0;
}

// writes BOTH ptr and cursor (cursor starts at segment base -> fill needs no ptr read)
__global__ void scan3_kernel(const int* __restrict__ excl, const int* __restrict__ boff,
                             int* __restrict__ ptr, int* __restrict__ cursor,
                             int n, int total)
{
    int i = blockIdx.x * blockDim.x + threadIdx.x;
    if (i < n) {
        int v = excl[i] + boff[i / SCAN_BLK];
        ptr[i] = v;
        cursor[i] = v;
    }
    if (i == 0) ptr[n] = total;
}

// ---------------------------------------------------------------------------
// CSR build step 3: fill sorted src-node list.
// cursor pre-initialized to segment bases (no ptr read). PLAIN store: ssrc is
// small (6.4 MB) and scattered 4B stores must merge in L2 — non-temporal
// stores measured 1.5x SLOWER here (round 9).
// ---------------------------------------------------------------------------
__global__ void fill_kernel(const int* __restrict__ src, const int* __restrict__ dst,
                            const int* __restrict__ et,
                            int* __restrict__ cursor, int* __restrict__ ssrc, int E)
{
    int e = blockIdx.x * blockDim.x + threadIdx.x;
    if (e < E) {
        int seg = dst[e] * RELS + et[e];
        int pos = atomicAdd(&cursor[seg], 1);
        ssrc[pos] = src[e];
    }
}

// ---------------------------------------------------------------------------
// Fused RGCN layer, wave-specialized compute, 512-thread blocks.
//  Phase 1 (gather): LPN lanes/node (LPN == IN/4: one float4 slice per lane),
//  NPB = 512/LPN nodes/block, 4x-unrolled CSR walk; the 4 relation means go
//  to LDS (row stride 4*IN+1, odd -> conflict-free column reads).
//  Phase 2 (compute): 8 waves; wave w -> node-block (w % NB) and channel
//  group (w / NB), lane = node. Weight rows are wave-uniform -> s_load (SMEM
//  pipe). Root term loads the lane's own feature row from global (L1-hot).
//  All instantiations: ~33 KB LDS -> 4 blocks/CU; __launch_bounds__(512,8)
//  caps VGPR at 64 -> 32 waves/CU (100%) ceiling.
// ---------------------------------------------------------------------------
template<int IN, int OUT, bool RELU, int LPN, int MINW>
__global__ __launch_bounds__(512, MINW)
void rgcn_layer_kernel(const float* __restrict__ feat,
                       const int* __restrict__ ptr, const int* __restrict__ ssrc,
                       const float* __restrict__ W, const float* __restrict__ root,
                       const float* __restrict__ bias,
                       float* __restrict__ hout, int n)
{
    constexpr int TPB = 512;
    constexpr int NPB = TPB / LPN;        // nodes per block (128 or 64)
    constexpr int K   = 4 * IN;           // staged: 4 relation means
    constexpr int AGS = K + 1;            // odd LDS row stride
    constexpr int F4  = IN / 4;           // float4 per feature row (== LPN)
    constexpr int Q   = OUT / LPN;        // channels per thread in phase 2
    constexpr int NB  = NPB / 64;         // node-blocks of 64 (1 or 2)

    static_assert(F4 == LPN, "one float4 slice per lane");

    __shared__ float agg[NPB * AGS];

    const int tid  = (int)threadIdx.x;
    const int nl   = tid / LPN;
    const int c4   = tid % LPN;
    const int node = (int)blockIdx.x * NPB + nl;

    const float4* fv = (const float4*)feat;

    // ---- phase 1: gather ----
    if (node < n) {
        int4 p4  = *(const int4*)(ptr + (size_t)node * RELS);
        int pend = ptr[(size_t)node * RELS + RELS];
        int pb[RELS + 1] = {p4.x, p4.y, p4.z, p4.w, pend};
        float* arow = &agg[nl * AGS];

        #pragma unroll
        for (int r = 0; r < RELS; ++r) {
            float4 ac = {0.f, 0.f, 0.f, 0.f};
            int p0 = pb[r], p1 = pb[r + 1];
            int e = p0;
            for (; e + 4 <= p1; e += 4) {
                int s0 = ssrc[e], s1 = ssrc[e + 1], s2 = ssrc[e + 2], s3 = ssrc[e + 3];
                float4 v0 = fv[(size_t)s0 * F4 + c4];
                float4 v1 = fv[(size_t)s1 * F4 + c4];
                float4 v2 = fv[(size_t)s2 * F4 + c4];
                float4 v3 = fv[(size_t)s3 * F4 + c4];
                ac.x += (v0.x + v1.x) + (v2.x + v3.x);
                ac.y += (v0.y + v1.y) + (v2.y + v3.y);
                ac.z += (v0.z + v1.z) + (v2.z + v3.z);
                ac.w += (v0.w + v1.w) + (v2.w + v3.w);
            }
            for (; e < p1; ++e) {
                int sn = ssrc[e];
                float4 v = fv[(size_t)sn * F4 + c4];
                ac.x += v.x; ac.y += v.y; ac.z += v.z; ac.w += v.w;
            }
            float nm = 1.0f / fmaxf((float)(p1 - p0), 1.0f);
            int kb = r * IN + c4 * 4;
            arow[kb + 0] = ac.x * nm;
            arow[kb + 1] = ac.y * nm;
            arow[kb + 2] = ac.z * nm;
            arow[kb + 3] = ac.w * nm;
        }
    }
    __syncthreads();

    // ---- phase 2: compute (wave -> (node-block, channel-group), lane -> node)
    const int wv   = __builtin_amdgcn_readfirstlane(tid >> 6);
    const int lane = tid & 63;
    const int nb   = wv % NB;             // node block within this workgroup
    const int cg   = wv / NB;             // channel group (wave-uniform)
    const int ln   = nb * 64 + lane;      // local node index
    const int cn   = (int)blockIdx.x * NPB + ln;
    const int cnc  = (cn < n) ? cn : (n - 1);

    const float* __restrict__ wq = W    + cg * Q;   // row stride OUT
    const float* __restrict__ rq = root + cg * Q;
    const float* __restrict__ bq = bias + cg * Q;
    const float* arow = &agg[ln * AGS];

    float acc[Q];
    #pragma unroll
    for (int o = 0; o < Q; ++o) acc[o] = bq[o];

    #pragma unroll 4
    for (int k = 0; k < K; ++k) {
        float m = arow[k];
        const float* wr = wq + (size_t)k * OUT;     // wave-uniform -> s_load
        #pragma unroll
        for (int o = 0; o < Q; ++o) acc[o] += m * wr[o];
    }
    // root term: own feature row, loaded float4-at-a-time (short live range)
    #pragma unroll
    for (int j = 0; j < F4; ++j) {
        float4 v = fv[(size_t)cnc * F4 + j];
        #pragma unroll
        for (int c = 0; c < 4; ++c) {
            float m = (&v.x)[c];
            const float* wr = rq + (size_t)(j * 4 + c) * OUT;   // wave-uniform
            #pragma unroll
            for (int o = 0; o < Q; ++o) acc[o] += m * wr[o];
        }
    }

    if (cn < n) {
        float* ho = hout + (size_t)cn * OUT + cg * Q;
        #pragma unroll
        for (int o = 0; o < Q; o += 4) {
            float4 v;
            v.x = RELU ? fmaxf(acc[o + 0], 0.f) : acc[o + 0];
            v.y = RELU ? fmaxf(acc[o + 1], 0.f) : acc[o + 1];
            v.z = RELU ? fmaxf(acc[o + 2], 0.f) : acc[o + 2];
            v.w = RELU ? fmaxf(acc[o + 3], 0.f) : acc[o + 3];
            *(float4*)(ho + o) = v;
        }
    }
}

// ---------------------------------------------------------------------------
// Segment-max pool: one block per graph, contiguous node range via binary
// search on sorted batch. Register max -> LDS reduce -> plain store.
// ---------------------------------------------------------------------------
__device__ inline int lower_bound_i(const int* a, int n, int key)
{
    int lo = 0, hi = n;
    while (lo < hi) { int mid = (lo + hi) >> 1; if (a[mid] < key) lo = mid + 1; else hi = mid; }
    return lo;
}

__global__ __launch_bounds__(256)
void pool_kernel(const float* __restrict__ h3, const int* __restrict__ batch,
                 float* __restrict__ gpool, int n)
{
    int g = blockIdx.x;
    int t = threadIdx.x;
    int ch = t & 63, q = t >> 6;

    int start = lower_bound_i(batch, n, g);
    int end   = lower_bound_i(batch, n, g + 1);

    float m = -INFINITY;
    for (int r = start + q; r < end; r += 4)
        m = fmaxf(m, h3[(size_t)r * 64 + ch]);

    __shared__ float red[4][64];
    red[q][ch] = m;
    __syncthreads();
    if (q == 0) {
        m = fmaxf(fmaxf(red[0][ch], red[1][ch]), fmaxf(red[2][ch], red[3][ch]));
        gpool[g * 64 + ch] = m;
    }
}

// ---------------------------------------------------------------------------
// MLP head: [G,64] -> 128 (relu) -> 256 (relu) -> 51 -> softmax. 1 block/graph.
// ---------------------------------------------------------------------------
__global__ __launch_bounds__(256)
void mlp_kernel(const float* __restrict__ gpool,
                const float* __restrict__ Wf1, const float* __restrict__ bf1,
                const float* __restrict__ Wh,  const float* __restrict__ bh,
                const float* __restrict__ Wl,  const float* __restrict__ bl,
                float* __restrict__ out)
{
    __shared__ float gin[64];
    __shared__ float f1[128];
    __shared__ float f2[256];
    __shared__ float lg[51];
    int g = blockIdx.x, t = threadIdx.x;

    if (t < 64) gin[t] = gpool[g * 64 + t];
    __syncthreads();

    if (t < 128) {
        float a = bf1[t];
        #pragma unroll 8
        for (int k = 0; k < 64; ++k) a += gin[k] * Wf1[k * 128 + t];
        f1[t] = fmaxf(a, 0.f);
    }
    __syncthreads();

    {
        float a = bh[t];
        #pragma unroll 8
        for (int k = 0; k < 128; ++k) a += f1[k] * Wh[k * 256 + t];
        f2[t] = fmaxf(a, 0.f);
    }
    __syncthreads();

    if (t < 51) {
        float a = bl[t];
        #pragma unroll 8
        for (int k = 0; k < 256; ++k) a += f2[k] * Wl[k * 51 + t];
        lg[t] = a;
    }
    __syncthreads();

    if (t == 0) {
        float m = lg[0];
        for (int i = 1; i < 51; ++i) m = fmaxf(m, lg[i]);
        float ssum = 0.f;
        for (int i = 0; i < 51; ++i) { float e = __expf(lg[i] - m); lg[i] = e; ssum += e; }
        float inv = 1.0f / ssum;
        for (int i = 0; i < 51; ++i) out[g * 51 + i] = lg[i] * inv;
    }
}

// ---------------------------------------------------------------------------
extern "C" void kernel_launch(void* const* d_in, const int* in_sizes, int n_in,
                              void* d_out, int out_size, void* d_ws, size_t ws_size,
                              hipStream_t stream)
{
    const float* x    = (const float*)d_in[0];
    const int*   ei   = (const int*)d_in[1];
    const int*   et   = (const int*)d_in[2];
    const int*   batch= (const int*)d_in[3];
    const float* W1   = (const float*)d_in[4];
    const float* r1   = (const float*)d_in[5];
    const float* b1   = (const float*)d_in[6];
    const float* W2   = (const float*)d_in[7];
    const float* r2   = (const float*)d_in[8];
    const float* b2   = (const float*)d_in[9];
    const float* W3   = (const float*)d_in[10];
    const float* r3   = (const float*)d_in[11];
    const float* b3   = (const float*)d_in[12];
    const float* Wf1  = (const float*)d_in[13];
    const float* bf1  = (const float*)d_in[14];
    const float* Wh   = (const float*)d_in[15];
    const float* bh   = (const float*)d_in[16];
    const float* Wl   = (const float*)d_in[17];
    const float* bl   = (const float*)d_in[18];

    const int N = in_sizes[0] / 16;
    const int E = in_sizes[2];
    const int NSEG = N * RELS;
    const int NBLK = (NSEG + SCAN_BLK - 1) / SCAN_BLK;
    const int* srcp = ei;
    const int* dstp = ei + E;

    char* ws = (char*)d_ws;
    size_t off = 0;
    int*   hcnt   = (int*)(ws + off);   off += alignup((size_t)NSEG * 4);
    int*   ptr    = (int*)(ws + off);   off += alignup((size_t)(NSEG + 1) * 4);
    int*   excl   = (int*)(ws + off);   off += alignup((size_t)NSEG * 4);
    int*   bsum   = (int*)(ws + off);   off += alignup(256 * 4);
    int*   boff   = (int*)(ws + off);   off += alignup(256 * 4);
    int*   cursor = (int*)(ws + off);   off += alignup((size_t)NSEG * 4);
    int*   ssrc   = (int*)(ws + off);   off += alignup((size_t)E * 4);
    float* h1     = (float*)(ws + off); off += alignup((size_t)N * 16 * 4);
    float* h2     = (float*)(ws + off); off += alignup((size_t)N * 32 * 4);
    float* h3     = (float*)(ws + off); off += alignup((size_t)N * 64 * 4);
    float* gpool  = (float*)(ws + off); off += alignup((size_t)NGRAPH * 64 * 4);
    (void)ws_size; (void)n_in; (void)out_size;

    // ---- build CSR (once per call; reused by all 3 layers)
    (void)hipMemsetAsync(hcnt, 0, (size_t)NSEG * 4, stream);
    hist_kernel<<<(E + 255) / 256, 256, 0, stream>>>(dstp, et, hcnt, E);
    scan1_kernel<<<NBLK, 256, 0, stream>>>(hcnt, excl, bsum, NSEG);
    scan2_kernel<<<1, 256, 0, stream>>>(bsum, boff, NBLK);
    scan3_kernel<<<(NSEG + 255) / 256, 256, 0, stream>>>(excl, boff, ptr, cursor, NSEG, E);
    fill_kernel<<<(E + 255) / 256, 256, 0, stream>>>(srcp, dstp, et, cursor, ssrc, E);

    // ---- three fused gather+transform layers (512-thread blocks)
    rgcn_layer_kernel<16, 16, true, 4, 8><<<(N + 127) / 128, 512, 0, stream>>>(
        x, ptr, ssrc, W1, r1, b1, h1, N);
    rgcn_layer_kernel<16, 32, true, 4, 8><<<(N + 127) / 128, 512, 0, stream>>>(
        h1, ptr, ssrc, W2, r2, b2, h2, N);
    rgcn_layer_kernel<32, 64, false, 8, 8><<<(N + 63) / 64, 512, 0, stream>>>(
        h2, ptr, ssrc, W3, r3, b3, h3, N);

    // ---- segment-max pool (no atomics)
    pool_kernel<<<NGRAPH, 256, 0, stream>>>(h3, batch, gpool, N);

    // ---- MLP head + softmax
    mlp_kernel<<<NGRAPH, 256, 0, stream>>>(gpool, Wf1, bf1, Wh, bh, Wl, bl, (float*)d_out);
}

// Round 11
// 332.467 us; speedup vs baseline: 1.1001x; 1.0741x over previous
//
#include <hip/hip_runtime.h>

#define RELS 4
#define NGRAPH 256
#define SCAN_BLK 2048   // elements per scan1 block (256 thr x 8)

static inline size_t alignup(size_t x) { return (x + 255) & ~(size_t)255; }

// ---------------------------------------------------------------------------
// CSR build step 1: histogram of segments seg = dst*R + et
// ---------------------------------------------------------------------------
__global__ void hist_kernel(const int* __restrict__ dst, const int* __restrict__ et,
                            int* __restrict__ hcnt, int E)
{
    int e = blockIdx.x * blockDim.x + threadIdx.x;
    if (e < E) atomicAdd(&hcnt[dst[e] * RELS + et[e]], 1);
}

// ---------------------------------------------------------------------------
// CSR build step 2: exclusive scan over NSEG bins (3 kernels)
// ---------------------------------------------------------------------------
__global__ __launch_bounds__(256)
void scan1_kernel(const int* __restrict__ in, int* __restrict__ excl,
                  int* __restrict__ bsum, int n)
{
    __shared__ int lds[256];
    int tid = threadIdx.x;
    int base = blockIdx.x * SCAN_BLK + tid * 8;
    int v[8];
    #pragma unroll
    for (int i = 0; i < 8; ++i) v[i] = (base + i < n) ? in[base + i] : 0;
    int run = 0;
    #pragma unroll
    for (int i = 0; i < 8; ++i) { int t = v[i]; v[i] = run; run += t; }
    lds[tid] = run;
    __syncthreads();
    for (int off = 1; off < 256; off <<= 1) {
        int t = (tid >= off) ? lds[tid - off] : 0;
        __syncthreads();
        lds[tid] += t;
        __syncthreads();
    }
    int ex = (tid > 0) ? lds[tid - 1] : 0;
    if (tid == 255) bsum[blockIdx.x] = lds[255];
    #pragma unroll
    for (int i = 0; i < 8; ++i) if (base + i < n) excl[base + i] = v[i] + ex;
}

__global__ __launch_bounds__(256)
void scan2_kernel(const int* __restrict__ bsum, int* __restrict__ boff, int nb)
{
    __shared__ int lds[256];
    int tid = threadIdx.x;
    lds[tid] = (tid < nb) ? bsum[tid] : 0;
    __syncthreads();
    for (int off = 1; off < 256; off <<= 1) {
        int t = (tid >= off) ? lds[tid - off] : 0;
        __syncthreads();
        lds[tid] += t;
        __syncthreads();
    }
    if (tid < nb) boff[tid] = (tid > 0) ? lds[tid - 1] : 0;
}

// writes BOTH ptr and cursor (cursor starts at segment base -> fill needs no ptr read)
__global__ void scan3_kernel(const int* __restrict__ excl, const int* __restrict__ boff,
                             int* __restrict__ ptr, int* __restrict__ cursor,
                             int n, int total)
{
    int i = blockIdx.x * blockDim.x + threadIdx.x;
    if (i < n) {
        int v = excl[i] + boff[i / SCAN_BLK];
        ptr[i] = v;
        cursor[i] = v;
    }
    if (i == 0) ptr[n] = total;
}

// ---------------------------------------------------------------------------
// CSR build step 3: fill sorted src-node list, dst-range BINNED.
// Pass p handles only edges with dst in [lo, hi): their ssrc positions form a
// contiguous ~E/P window (ptr is monotone in seg) that fits in one XCD's L2,
// so the scattered 4B stores merge into full lines before writeback
// (write traffic ~window size instead of 64B per edge).
// ---------------------------------------------------------------------------
__global__ void fill_pass_kernel(const int* __restrict__ src, const int* __restrict__ dst,
                                 const int* __restrict__ et,
                                 int* __restrict__ cursor, int* __restrict__ ssrc,
                                 int E, int lo, int hi)
{
    int e = blockIdx.x * blockDim.x + threadIdx.x;
    if (e < E) {
        int d = dst[e];
        if (d >= lo && d < hi) {
            int seg = d * RELS + et[e];
            int pos = atomicAdd(&cursor[seg], 1);
            ssrc[pos] = src[e];
        }
    }
}

// ---------------------------------------------------------------------------
// Fused RGCN layer, wave-specialized compute, 512-thread blocks.
//  Phase 1 (gather): LPN lanes/node (LPN == IN/4: one float4 slice per lane),
//  NPB = 512/LPN nodes/block, 4x-unrolled CSR walk; the 4 relation means go
//  to LDS (row stride 4*IN+1, odd -> conflict-free column reads).
//  Phase 2 (compute): 8 waves; wave w -> node-block (w % NB) and channel
//  group (w / NB), lane = node. Weight rows are wave-uniform -> s_load (SMEM
//  pipe). Root term loads the lane's own feature row from global (L1-hot).
// ---------------------------------------------------------------------------
template<int IN, int OUT, bool RELU, int LPN, int MINW>
__global__ __launch_bounds__(512, MINW)
void rgcn_layer_kernel(const float* __restrict__ feat,
                       const int* __restrict__ ptr, const int* __restrict__ ssrc,
                       const float* __restrict__ W, const float* __restrict__ root,
                       const float* __restrict__ bias,
                       float* __restrict__ hout, int n)
{
    constexpr int TPB = 512;
    constexpr int NPB = TPB / LPN;        // nodes per block (128 or 64)
    constexpr int K   = 4 * IN;           // staged: 4 relation means
    constexpr int AGS = K + 1;            // odd LDS row stride
    constexpr int F4  = IN / 4;           // float4 per feature row (== LPN)
    constexpr int Q   = OUT / LPN;        // channels per thread in phase 2
    constexpr int NB  = NPB / 64;         // node-blocks of 64 (1 or 2)

    static_assert(F4 == LPN, "one float4 slice per lane");

    __shared__ float agg[NPB * AGS];

    const int tid  = (int)threadIdx.x;
    const int nl   = tid / LPN;
    const int c4   = tid % LPN;
    const int node = (int)blockIdx.x * NPB + nl;

    const float4* fv = (const float4*)feat;

    // ---- phase 1: gather ----
    if (node < n) {
        int4 p4  = *(const int4*)(ptr + (size_t)node * RELS);
        int pend = ptr[(size_t)node * RELS + RELS];
        int pb[RELS + 1] = {p4.x, p4.y, p4.z, p4.w, pend};
        float* arow = &agg[nl * AGS];

        #pragma unroll
        for (int r = 0; r < RELS; ++r) {
            float4 ac = {0.f, 0.f, 0.f, 0.f};
            int p0 = pb[r], p1 = pb[r + 1];
            int e = p0;
            for (; e + 4 <= p1; e += 4) {
                int s0 = ssrc[e], s1 = ssrc[e + 1], s2 = ssrc[e + 2], s3 = ssrc[e + 3];
                float4 v0 = fv[(size_t)s0 * F4 + c4];
                float4 v1 = fv[(size_t)s1 * F4 + c4];
                float4 v2 = fv[(size_t)s2 * F4 + c4];
                float4 v3 = fv[(size_t)s3 * F4 + c4];
                ac.x += (v0.x + v1.x) + (v2.x + v3.x);
                ac.y += (v0.y + v1.y) + (v2.y + v3.y);
                ac.z += (v0.z + v1.z) + (v2.z + v3.z);
                ac.w += (v0.w + v1.w) + (v2.w + v3.w);
            }
            for (; e < p1; ++e) {
                int sn = ssrc[e];
                float4 v = fv[(size_t)sn * F4 + c4];
                ac.x += v.x; ac.y += v.y; ac.z += v.z; ac.w += v.w;
            }
            float nm = 1.0f / fmaxf((float)(p1 - p0), 1.0f);
            int kb = r * IN + c4 * 4;
            arow[kb + 0] = ac.x * nm;
            arow[kb + 1] = ac.y * nm;
            arow[kb + 2] = ac.z * nm;
            arow[kb + 3] = ac.w * nm;
        }
    }
    __syncthreads();

    // ---- phase 2: compute (wave -> (node-block, channel-group), lane -> node)
    const int wv   = __builtin_amdgcn_readfirstlane(tid >> 6);
    const int lane = tid & 63;
    const int nb   = wv % NB;             // node block within this workgroup
    const int cg   = wv / NB;             // channel group (wave-uniform)
    const int ln   = nb * 64 + lane;      // local node index
    const int cn   = (int)blockIdx.x * NPB + ln;
    const int cnc  = (cn < n) ? cn : (n - 1);

    const float* __restrict__ wq = W    + cg * Q;   // row stride OUT
    const float* __restrict__ rq = root + cg * Q;
    const float* __restrict__ bq = bias + cg * Q;
    const float* arow = &agg[ln * AGS];

    float acc[Q];
    #pragma unroll
    for (int o = 0; o < Q; ++o) acc[o] = bq[o];

    #pragma unroll 4
    for (int k = 0; k < K; ++k) {
        float m = arow[k];
        const float* wr = wq + (size_t)k * OUT;     // wave-uniform -> s_load
        #pragma unroll
        for (int o = 0; o < Q; ++o) acc[o] += m * wr[o];
    }
    // root term: own feature row, loaded float4-at-a-time (short live range)
    #pragma unroll
    for (int j = 0; j < F4; ++j) {
        float4 v = fv[(size_t)cnc * F4 + j];
        #pragma unroll
        for (int c = 0; c < 4; ++c) {
            float m = (&v.x)[c];
            const float* wr = rq + (size_t)(j * 4 + c) * OUT;   // wave-uniform
            #pragma unroll
            for (int o = 0; o < Q; ++o) acc[o] += m * wr[o];
        }
    }

    if (cn < n) {
        float* ho = hout + (size_t)cn * OUT + cg * Q;
        #pragma unroll
        for (int o = 0; o < Q; o += 4) {
            float4 v;
            v.x = RELU ? fmaxf(acc[o + 0], 0.f) : acc[o + 0];
            v.y = RELU ? fmaxf(acc[o + 1], 0.f) : acc[o + 1];
            v.z = RELU ? fmaxf(acc[o + 2], 0.f) : acc[o + 2];
            v.w = RELU ? fmaxf(acc[o + 3], 0.f) : acc[o + 3];
            *(float4*)(ho + o) = v;
        }
    }
}

// ---------------------------------------------------------------------------
// Segment-max pool: one block per graph, contiguous node range via binary
// search on sorted batch. Register max -> LDS reduce -> plain store.
// ---------------------------------------------------------------------------
__device__ inline int lower_bound_i(const int* a, int n, int key)
{
    int lo = 0, hi = n;
    while (lo < hi) { int mid = (lo + hi) >> 1; if (a[mid] < key) lo = mid + 1; else hi = mid; }
    return lo;
}

__global__ __launch_bounds__(256)
void pool_kernel(const float* __restrict__ h3, const int* __restrict__ batch,
                 float* __restrict__ gpool, int n)
{
    int g = blockIdx.x;
    int t = threadIdx.x;
    int ch = t & 63, q = t >> 6;

    int start = lower_bound_i(batch, n, g);
    int end   = lower_bound_i(batch, n, g + 1);

    float m = -INFINITY;
    for (int r = start + q; r < end; r += 4)
        m = fmaxf(m, h3[(size_t)r * 64 + ch]);

    __shared__ float red[4][64];
    red[q][ch] = m;
    __syncthreads();
    if (q == 0) {
        m = fmaxf(fmaxf(red[0][ch], red[1][ch]), fmaxf(red[2][ch], red[3][ch]));
        gpool[g * 64 + ch] = m;
    }
}

// ---------------------------------------------------------------------------
// MLP head: [G,64] -> 128 (relu) -> 256 (relu) -> 51 -> softmax. 1 block/graph.
// ---------------------------------------------------------------------------
__global__ __launch_bounds__(256)
void mlp_kernel(const float* __restrict__ gpool,
                const float* __restrict__ Wf1, const float* __restrict__ bf1,
                const float* __restrict__ Wh,  const float* __restrict__ bh,
                const float* __restrict__ Wl,  const float* __restrict__ bl,
                float* __restrict__ out)
{
    __shared__ float gin[64];
    __shared__ float f1[128];
    __shared__ float f2[256];
    __shared__ float lg[51];
    int g = blockIdx.x, t = threadIdx.x;

    if (t < 64) gin[t] = gpool[g * 64 + t];
    __syncthreads();

    if (t < 128) {
        float a = bf1[t];
        #pragma unroll 8
        for (int k = 0; k < 64; ++k) a += gin[k] * Wf1[k * 128 + t];
        f1[t] = fmaxf(a, 0.f);
    }
    __syncthreads();

    {
        float a = bh[t];
        #pragma unroll 8
        for (int k = 0; k < 128; ++k) a += f1[k] * Wh[k * 256 + t];
        f2[t] = fmaxf(a, 0.f);
    }
    __syncthreads();

    if (t < 51) {
        float a = bl[t];
        #pragma unroll 8
        for (int k = 0; k < 256; ++k) a += f2[k] * Wl[k * 51 + t];
        lg[t] = a;
    }
    __syncthreads();

    if (t == 0) {
        float m = lg[0];
        for (int i = 1; i < 51; ++i) m = fmaxf(m, lg[i]);
        float ssum = 0.f;
        for (int i = 0; i < 51; ++i) { float e = __expf(lg[i] - m); lg[i] = e; ssum += e; }
        float inv = 1.0f / ssum;
        for (int i = 0; i < 51; ++i) out[g * 51 + i] = lg[i] * inv;
    }
}

// ---------------------------------------------------------------------------
extern "C" void kernel_launch(void* const* d_in, const int* in_sizes, int n_in,
                              void* d_out, int out_size, void* d_ws, size_t ws_size,
                              hipStream_t stream)
{
    const float* x    = (const float*)d_in[0];
    const int*   ei   = (const int*)d_in[1];
    const int*   et   = (const int*)d_in[2];
    const int*   batch= (const int*)d_in[3];
    const float* W1   = (const float*)d_in[4];
    const float* r1   = (const float*)d_in[5];
    const float* b1   = (const float*)d_in[6];
    const float* W2   = (const float*)d_in[7];
    const float* r2   = (const float*)d_in[8];
    const float* b2   = (const float*)d_in[9];
    const float* W3   = (const float*)d_in[10];
    const float* r3   = (const float*)d_in[11];
    const float* b3   = (const float*)d_in[12];
    const float* Wf1  = (const float*)d_in[13];
    const float* bf1  = (const float*)d_in[14];
    const float* Wh   = (const float*)d_in[15];
    const float* bh   = (const float*)d_in[16];
    const float* Wl   = (const float*)d_in[17];
    const float* bl   = (const float*)d_in[18];

    const int N = in_sizes[0] / 16;
    const int E = in_sizes[2];
    const int NSEG = N * RELS;
    const int NBLK = (NSEG + SCAN_BLK - 1) / SCAN_BLK;
    const int* srcp = ei;
    const int* dstp = ei + E;

    char* ws = (char*)d_ws;
    size_t off = 0;
    int*   hcnt   = (int*)(ws + off);   off += alignup((size_t)NSEG * 4);
    int*   ptr    = (int*)(ws + off);   off += alignup((size_t)(NSEG + 1) * 4);
    int*   excl   = (int*)(ws + off);   off += alignup((size_t)NSEG * 4);
    int*   bsum   = (int*)(ws + off);   off += alignup(256 * 4);
    int*   boff   = (int*)(ws + off);   off += alignup(256 * 4);
    int*   cursor = (int*)(ws + off);   off += alignup((size_t)NSEG * 4);
    int*   ssrc   = (int*)(ws + off);   off += alignup((size_t)E * 4);
    float* h1     = (float*)(ws + off); off += alignup((size_t)N * 16 * 4);
    float* h2     = (float*)(ws + off); off += alignup((size_t)N * 32 * 4);
    float* h3     = (float*)(ws + off); off += alignup((size_t)N * 64 * 4);
    float* gpool  = (float*)(ws + off); off += alignup((size_t)NGRAPH * 64 * 4);
    (void)ws_size; (void)n_in; (void)out_size;

    // ---- build CSR (once per call; reused by all 3 layers)
    (void)hipMemsetAsync(hcnt, 0, (size_t)NSEG * 4, stream);
    hist_kernel<<<(E + 255) / 256, 256, 0, stream>>>(dstp, et, hcnt, E);
    scan1_kernel<<<NBLK, 256, 0, stream>>>(hcnt, excl, bsum, NSEG);
    scan2_kernel<<<1, 256, 0, stream>>>(bsum, boff, NBLK);
    scan3_kernel<<<(NSEG + 255) / 256, 256, 0, stream>>>(excl, boff, ptr, cursor, NSEG, E);

    // binned fill: 4 passes over dst-quarters; each pass's ssrc window (~E/4
    // ints) is L2-resident so scattered stores merge before writeback
    {
        const int P = 4;
        for (int p = 0; p < P; ++p) {
            int lo = (int)((long long)N * p / P);
            int hi = (int)((long long)N * (p + 1) / P);
            fill_pass_kernel<<<(E + 255) / 256, 256, 0, stream>>>(
                srcp, dstp, et, cursor, ssrc, E, lo, hi);
        }
    }

    // ---- three fused gather+transform layers (512-thread blocks)
    rgcn_layer_kernel<16, 16, true, 4, 8><<<(N + 127) / 128, 512, 0, stream>>>(
        x, ptr, ssrc, W1, r1, b1, h1, N);
    rgcn_layer_kernel<16, 32, true, 4, 8><<<(N + 127) / 128, 512, 0, stream>>>(
        h1, ptr, ssrc, W2, r2, b2, h2, N);
    rgcn_layer_kernel<32, 64, false, 8, 8><<<(N + 63) / 64, 512, 0, stream>>>(
        h2, ptr, ssrc, W3, r3, b3, h3, N);

    // ---- segment-max pool (no atomics)
    pool_kernel<<<NGRAPH, 256, 0, stream>>>(h3, batch, gpool, N);

    // ---- MLP head + softmax
    mlp_kernel<<<NGRAPH, 256, 0, stream>>>(gpool, Wf1, bf1, Wh, bh, Wl, bl, (float*)d_out);
}